// Round 4
// baseline (356.213 us; speedup 1.0000x reference)
//
#include <hip/hip_runtime.h>

// DynamiConv via implicit-im2col f16 MFMA; gate as f32 tap-partials in LDS:
//   out[b,o,y,x] = gate[b,y,x] * (W . cols)[o] + bias[o]
//   gate[y,x] = sum_tap gpart[tap][y+ki-1,x+kj-1],
//   gpart[tap][pos] = sum_c dW[c,tap]*sigmoid(x[c,pos])   (built by LDS atomics at staging)
// Gate is one scalar per lane (acc column = one spatial position).
// x[8,32,256,256] f32, W[32,32,3,3], dW[1,32,3,3], bias[32] -> out[8,32,256,256] f32

typedef _Float16 half8 __attribute__((ext_vector_type(8)));
typedef _Float16 half4 __attribute__((ext_vector_type(4)));
typedef float f32x4 __attribute__((ext_vector_type(4)));
typedef float f32x16 __attribute__((ext_vector_type(16)));

#define BATCH 8
#define CIN 32
#define COUT 32
#define HH 256
#define WW 256
#define TW 32           // spatial tile width (one MFMA n-tile)
#define TH 8            // spatial tile height (8 n-rows, 1 per wave, 512 thr)
#define HTW 34
#define HTH 10
#define CSTR 40         // f16 per position (32 ch + 8 pad) = 80 B stride, 16B-aligned frags
#define NCHUNK 18       // K=288 as 18 chunks of 16: chunk q -> tap=q>>1, c-half=q&1
#define NPOS (HTH*HTW)  // 340 halo positions
#define NITEM (NPOS*8)  // 2720 staging items (4 channels each)

// Apack = W in per-lane MFMA A order (o=lane&31, c=(q&1)*16+(lane>>5)*8+j, tap=q>>1).
// dwpack[cg][tap][u] = dW[cg*4+u][tap]  (288 f32) for the staging-time gate dots.
__global__ __launch_bounds__(256) void prep_pack(const float* __restrict__ w,
                                                 const float* __restrict__ dw,
                                                 _Float16* __restrict__ Apack,
                                                 float* __restrict__ dwpack) {
  int t = blockIdx.x * 256 + threadIdx.x;
  if (t < 9216) {
    int q = t >> 9, lane = (t >> 3) & 63, j = t & 7;
    int tap = q >> 1, h = q & 1;
    int o = lane & 31, lh = lane >> 5;
    int c = h * 16 + lh * 8 + j;
    Apack[t] = (_Float16)w[o * 288 + c * 9 + tap];
  } else if (t < 9216 + 288) {
    int i = t - 9216;
    int cg = i / 36, r = i - cg * 36;
    int tap = r >> 2, u = r & 3;
    dwpack[i] = dw[(cg * 4 + u) * 9 + tap];
  }
}

__global__ __launch_bounds__(512, 8) void dynconv(
    const float* __restrict__ x, const _Float16* __restrict__ Apack,
    const float* __restrict__ dwpack, const float* __restrict__ bias,
    float* __restrict__ out) {
  __shared__ __align__(16) _Float16 lv[NPOS * CSTR];   // 27200 B f16 values
  __shared__ float gpart[9 * NPOS];                    // 12240 B gate tap-partials

  // XCD-batch swizzle: XCD k handles batch k; neighbors' halos stay in its L2.
  const int bid0 = blockIdx.x;              // grid = 2048
  const int bb = bid0 & 7, idx = bid0 >> 3;
  const int xt = idx & 7, yt = idx >> 3;    // yt < 32
  const int x0 = xt * TW, y0 = yt * TH;
  const int tid = threadIdx.x;

  // zero gate partials before atomics
  for (int i = tid; i < 9 * NPOS; i += 512) gpart[i] = 0.f;
  __syncthreads();

  // ---- stage: f16 values -> LDS [pos][c]; gate tap-partials via ds_add_f32 ----
  for (int i = tid; i < NITEM; i += 512) {
    const int cg = i / NPOS;                // channel group 0..7 (4 ch)
    const int pos = i - cg * NPOS;
    const int yy = pos / HTW;
    const int xx = pos - yy * HTW;
    const int gy = y0 + yy - 1, gx = x0 + xx - 1;
    float v0 = 0.f, v1 = 0.f, v2 = 0.f, v3 = 0.f;
    if ((unsigned)gy < 256u && (unsigned)gx < 256u) {
      const float* xp = x + (((size_t)(bb * CIN + cg * 4)) << 16) + (gy << 8) + gx;
      v0 = xp[0]; v1 = xp[1 << 16]; v2 = xp[2 << 16]; v3 = xp[3 << 16];
    }
    const float s0 = __builtin_amdgcn_rcpf(1.f + __expf(-v0));
    const float s1 = __builtin_amdgcn_rcpf(1.f + __expf(-v1));
    const float s2 = __builtin_amdgcn_rcpf(1.f + __expf(-v2));
    const float s3 = __builtin_amdgcn_rcpf(1.f + __expf(-v3));
    half4 hv = {(_Float16)v0, (_Float16)v1, (_Float16)v2, (_Float16)v3};
    *(half4*)(lv + pos * CSTR + cg * 4) = hv;
    const float* dwp = dwpack + cg * 36;
#pragma unroll
    for (int tap = 0; tap < 9; ++tap) {
      const f32x4 d = *(const f32x4*)(dwp + tap * 4);
      atomicAdd(&gpart[tap * NPOS + pos], d[0] * s0 + d[1] * s1 + d[2] * s2 + d[3] * s3);
    }
  }
  __syncthreads();

  // ---- compute: wave w8 owns tile row y0+w8; 18 chunks, 1 MFMA each ----
  const int lane = tid & 63, w8 = tid >> 6;
  const int ln = lane & 31, lh = lane >> 5;

  // per-lane gate: gather 9 tap-partials around this lane's output position
  float gate = 0.f;
#pragma unroll
  for (int ki = 0; ki < 3; ++ki)
#pragma unroll
    for (int kj = 0; kj < 3; ++kj)
      gate += gpart[(ki * 3 + kj) * NPOS + (w8 + ki) * HTW + ln + kj];

  f32x16 acc;
#pragma unroll
  for (int i = 0; i < 16; ++i) acc[i] = 0.f;

#pragma unroll
  for (int q = 0; q < NCHUNK; ++q) {
    const int tap = q >> 1, h = q & 1;
    const int ki = tap / 3, kj = tap - ki * 3;
    const half8 a = *(const half8*)(Apack + ((q * 64 + lane) << 3));  // L1-hot
    const int off = ((w8 + ki) * HTW + ln + kj) * CSTR + h * 16 + lh * 8;
    const half8 bv = *(const half8*)(lv + off);   // ds_read_b128
    acc = __builtin_amdgcn_mfma_f32_32x32x16_f16(a, bv, acc, 0, 0, 0);
  }

  // ---- epilogue: D layout col=lane&31, row=(reg&3)+8*(reg>>2)+4*(lane>>5) ----
  const int y = y0 + w8;
#pragma unroll
  for (int reg = 0; reg < 16; ++reg) {
    const int o = (reg & 3) + 8 * (reg >> 2) + 4 * lh;
    out[(((size_t)(bb * COUT + o)) << 16) + (y << 8) + x0 + ln] =
        acc[reg] * gate + bias[o];
  }
}

extern "C" void kernel_launch(void* const* d_in, const int* in_sizes, int n_in,
                              void* d_out, int out_size, void* d_ws, size_t ws_size,
                              hipStream_t stream) {
  const float* x    = (const float*)d_in[0];
  const float* wgt  = (const float*)d_in[1];
  const float* dw   = (const float*)d_in[2];
  const float* bias = (const float*)d_in[3];
  float* out = (float*)d_out;

  _Float16* Apack = (_Float16*)d_ws;                       // 9216 f16 = 18432 B
  float* dwpack   = (float*)((char*)d_ws + 18432);         // 288 f32

  prep_pack<<<(9216 + 288 + 255) / 256, 256, 0, stream>>>(wgt, dw, Apack, dwpack);
  dynconv<<<BATCH * (HH / TH) * (WW / TW), 512, 0, stream>>>(x, Apack, dwpack, bias, out);
}

// Round 5
// 144.600 us; speedup vs baseline: 2.4634x; 2.4634x over previous
//
#include <hip/hip_runtime.h>

// DynamiConv via implicit-im2col f16 MFMA; gate via per-position tap-partials
// computed by a dedicated owner thread (NO atomics):
//   out[b,o,y,x] = gate[b,y,x] * (W . cols)[o] + bias[o]
//   gpart[tap][pos] = sum_c dW[c,tap]*sigmoid(v[c,pos]);  gate = sum_tap gpart[tap][pos+off(tap)]
// x[8,32,256,256] f32, W[32,32,3,3], dW[1,32,3,3], bias[32] -> out[8,32,256,256] f32

typedef _Float16 half8 __attribute__((ext_vector_type(8)));
typedef _Float16 half4 __attribute__((ext_vector_type(4)));
typedef float f32x16 __attribute__((ext_vector_type(16)));

#define BATCH 8
#define CIN 32
#define COUT 32
#define HH 256
#define WW 256
#define TW 32           // spatial tile width (one MFMA n-tile)
#define TH 8            // spatial tile height (8 n-rows, 1 per wave, 512 thr)
#define HTW 34
#define HTH 10
#define CSTR 40         // f16 per position (32 ch + 8 pad) = 80 B stride, 16B-aligned frags
#define NCHUNK 18       // K=288 as 18 chunks of 16: chunk q -> tap=q>>1, c-half=q&1
#define NPOS (HTH*HTW)  // 340 halo positions
#define NITEM (NPOS*8)  // 2720 staging items (4 channels each)

// Apack = W in per-lane MFMA A order (o=lane&31, c=(q&1)*16+(lane>>5)*8+j, tap=q>>1).
// dwf[tap][c] = dW[c][tap] (288 f32, tap-major) for phase-B gate dots (wave-uniform).
__global__ __launch_bounds__(256) void prep_pack(const float* __restrict__ w,
                                                 const float* __restrict__ dw,
                                                 _Float16* __restrict__ Apack,
                                                 float* __restrict__ dwf) {
  int t = blockIdx.x * 256 + threadIdx.x;
  if (t < 9216) {
    int q = t >> 9, lane = (t >> 3) & 63, j = t & 7;
    int tap = q >> 1, h = q & 1;
    int o = lane & 31, lh = lane >> 5;
    int c = h * 16 + lh * 8 + j;
    Apack[t] = (_Float16)w[o * 288 + c * 9 + tap];
  } else if (t < 9216 + 288) {
    int i = t - 9216;
    int tap = i >> 5, c = i & 31;
    dwf[i] = dw[c * 9 + tap];
  }
}

__global__ __launch_bounds__(512, 4) void dynconv(
    const float* __restrict__ x, const _Float16* __restrict__ Apack,
    const float* __restrict__ dwf, const float* __restrict__ bias,
    float* __restrict__ out) {
  __shared__ __align__(16) _Float16 lv[NPOS * CSTR];   // 27200 B f16 values
  __shared__ float gpart[9 * NPOS];                    // 12240 B gate tap-partials

  // XCD-batch swizzle: XCD k handles batch k; halo re-reads stay in its L2/L3.
  const int bid0 = blockIdx.x;              // grid = 2048
  const int bb = bid0 & 7, idx = bid0 >> 3;
  const int xt = idx & 7, yt = idx >> 3;    // yt < 32
  const int x0 = xt * TW, y0 = yt * TH;
  const int tid = threadIdx.x;

  // ---- phase A: stage f16 values -> LDS [pos][c], coalesced, no sigmoid ----
  for (int i = tid; i < NITEM; i += 512) {
    const int cg = i / NPOS;                // channel group 0..7 (4 ch)
    const int pos = i - cg * NPOS;
    const int yy = pos / HTW;
    const int xx = pos - yy * HTW;
    const int gy = y0 + yy - 1, gx = x0 + xx - 1;
    float v0 = 0.f, v1 = 0.f, v2 = 0.f, v3 = 0.f;
    if ((unsigned)gy < 256u && (unsigned)gx < 256u) {
      const float* xp = x + (((size_t)(bb * CIN + cg * 4)) << 16) + (gy << 8) + gx;
      v0 = xp[0]; v1 = xp[1 << 16]; v2 = xp[2 << 16]; v3 = xp[3 << 16];
    }
    half4 hv = {(_Float16)v0, (_Float16)v1, (_Float16)v2, (_Float16)v3};
    *(half4*)(lv + pos * CSTR + cg * 4) = hv;
  }
  __syncthreads();

  // ---- phase B: one thread per position computes 9 tap-partials, plain writes ----
  if (tid < NPOS) {
    const _Float16* base = lv + tid * CSTR;
    float p[9];
#pragma unroll
    for (int tap = 0; tap < 9; ++tap) p[tap] = 0.f;
    for (int c = 0; c < CIN; ++c) {
      const float v = (float)base[c];
      const float s = __builtin_amdgcn_rcpf(1.f + __expf(-v));
#pragma unroll
      for (int tap = 0; tap < 9; ++tap)
        p[tap] += dwf[tap * 32 + c] * s;     // dwf addr wave-uniform -> SGPR operand
    }
#pragma unroll
    for (int tap = 0; tap < 9; ++tap)
      gpart[tap * NPOS + tid] = p[tap];      // exclusive owner: plain ds_write_b32
  }
  __syncthreads();

  // ---- compute: wave w8 owns tile row y0+w8; 18 chunks, 1 MFMA each ----
  const int lane = tid & 63, w8 = tid >> 6;
  const int ln = lane & 31, lh = lane >> 5;

  // per-lane gate: gather 9 tap-partials around this lane's output position
  float gate = 0.f;
#pragma unroll
  for (int ki = 0; ki < 3; ++ki)
#pragma unroll
    for (int kj = 0; kj < 3; ++kj)
      gate += gpart[(ki * 3 + kj) * NPOS + (w8 + ki) * HTW + ln + kj];

  f32x16 acc;
#pragma unroll
  for (int i = 0; i < 16; ++i) acc[i] = 0.f;

#pragma unroll
  for (int q = 0; q < NCHUNK; ++q) {
    const int tap = q >> 1, h = q & 1;
    const int ki = tap / 3, kj = tap - ki * 3;
    const half8 a = *(const half8*)(Apack + ((q * 64 + lane) << 3));  // L1-hot
    const int off = ((w8 + ki) * HTW + ln + kj) * CSTR + h * 16 + lh * 8;
    const half8 bv = *(const half8*)(lv + off);   // ds_read_b128
    acc = __builtin_amdgcn_mfma_f32_32x32x16_f16(a, bv, acc, 0, 0, 0);
  }

  // ---- epilogue: D layout col=lane&31, row=(reg&3)+8*(reg>>2)+4*(lane>>5) ----
  const int y = y0 + w8;
#pragma unroll
  for (int reg = 0; reg < 16; ++reg) {
    const int o = (reg & 3) + 8 * (reg >> 2) + 4 * lh;
    out[(((size_t)(bb * COUT + o)) << 16) + (y << 8) + x0 + ln] =
        acc[reg] * gate + bias[o];
  }
}

extern "C" void kernel_launch(void* const* d_in, const int* in_sizes, int n_in,
                              void* d_out, int out_size, void* d_ws, size_t ws_size,
                              hipStream_t stream) {
  const float* x    = (const float*)d_in[0];
  const float* wgt  = (const float*)d_in[1];
  const float* dw   = (const float*)d_in[2];
  const float* bias = (const float*)d_in[3];
  float* out = (float*)d_out;

  _Float16* Apack = (_Float16*)d_ws;                 // 9216 f16 = 18432 B
  float* dwf      = (float*)((char*)d_ws + 18432);   // 288 f32

  prep_pack<<<(9216 + 288 + 255) / 256, 256, 0, stream>>>(wgt, dw, Apack, dwf);
  dynconv<<<BATCH * (HH / TH) * (WW / TW), 512, 0, stream>>>(x, Apack, dwf, bias, out);
}

// Round 6
// 133.767 us; speedup vs baseline: 2.6629x; 1.0810x over previous
//
#include <hip/hip_runtime.h>

// DynamiConv via implicit-im2col f16 MFMA; single-barrier structure:
//   staging thread owns ONE halo position: loads its 32 channels (uniform voff +
//   per-channel SGPR base), computes sigma once, 9 gate tap-partials in regs,
//   writes f16 values + gpart to LDS. Then 1 barrier, then MFMA K-loop.
//   out[b,o,y,x] = gate[b,y,x]*(W.cols)[o] + bias[o];
//   gate = sum_tap gpart[tap][pos+off(tap)], gpart = dW[:,tap].sigma(v[:,pos])
// x[8,32,256,256] f32, W[32,32,3,3], dW[1,32,3,3], bias[32] -> out[8,32,256,256] f32

typedef _Float16 half8 __attribute__((ext_vector_type(8)));
typedef float f32x16 __attribute__((ext_vector_type(16)));

#define BATCH 8
#define CIN 32
#define COUT 32
#define HH 256
#define WW 256
#define TW 32           // spatial tile width (one MFMA n-tile)
#define TH 4            // spatial tile height: 4 rows, 1 per wave, 256 thr
#define HTW 34
#define HTH 6
#define CSTR 40         // f16 per position (32 ch + 8 pad) = 80 B stride
#define NCHUNK 18       // K=288 as 18 chunks of 16: chunk q -> tap=q>>1, c-half=q&1
#define NPOS (HTH*HTW)  // 204 halo positions (<= 256 threads: one owner each)

// Apack = W in per-lane MFMA A order (o=lane&31, c=(q&1)*16+(lane>>5)*8+j, tap=q>>1).
// dwf[tap][c] = dW[c][tap] (288 f32, tap-major; wave-uniform reads at staging).
__global__ __launch_bounds__(256) void prep_pack(const float* __restrict__ w,
                                                 const float* __restrict__ dw,
                                                 _Float16* __restrict__ Apack,
                                                 float* __restrict__ dwf) {
  int t = blockIdx.x * 256 + threadIdx.x;
  if (t < 9216) {
    int q = t >> 9, lane = (t >> 3) & 63, j = t & 7;
    int tap = q >> 1, h = q & 1;
    int o = lane & 31, lh = lane >> 5;
    int c = h * 16 + lh * 8 + j;
    Apack[t] = (_Float16)w[o * 288 + c * 9 + tap];
  } else if (t < 9216 + 288) {
    int i = t - 9216;
    int tap = i >> 5, c = i & 31;
    dwf[i] = dw[c * 9 + tap];
  }
}

__global__ __launch_bounds__(256, 6) void dynconv(
    const float* __restrict__ x, const _Float16* __restrict__ Apack,
    const float* __restrict__ dwf, const float* __restrict__ bias,
    float* __restrict__ out) {
  __shared__ __align__(16) _Float16 lv[NPOS * CSTR];   // 16320 B f16 values
  __shared__ float gpart[9 * NPOS];                    // 7344 B gate tap-partials

  // XCD-batch swizzle: XCD k handles batch k; halo re-reads stay in its L2.
  const int bid0 = blockIdx.x;              // grid = 4096
  const int bb = bid0 & 7, idx = bid0 >> 3;
  const int xt = idx & 7, yt = idx >> 3;    // yt < 64
  const int x0 = xt * TW, y0 = yt * TH;
  const int tid = threadIdx.x;

  // ---- staging: one owner thread per halo position, single pass ----
  if (tid < NPOS) {
    const int yy = tid / HTW, xx = tid - (tid / HTW) * HTW;
    const int gy = y0 + yy - 1, gx = x0 + xx - 1;
    const int voff = (gy << 8) + gx;        // uniform across c -> saddr-form loads
    float v[CIN];
    if ((unsigned)gy < 256u && (unsigned)gx < 256u) {
#pragma unroll
      for (int c = 0; c < CIN; ++c)
        v[c] = x[(((size_t)(bb * CIN + c)) << 16) + voff];  // 32-deep MLP
    } else {
#pragma unroll
      for (int c = 0; c < CIN; ++c) v[c] = 0.f;
    }
    float p[9];
#pragma unroll
    for (int tap = 0; tap < 9; ++tap) p[tap] = 0.f;
    _Float16 hv[CIN];
#pragma unroll
    for (int c = 0; c < CIN; ++c) {
      const float s = __builtin_amdgcn_rcpf(1.f + __expf(-v[c]));
#pragma unroll
      for (int tap = 0; tap < 9; ++tap)
        p[tap] += dwf[tap * 32 + c] * s;    // dwf uniform -> SGPR operand
      hv[c] = (_Float16)v[c];
    }
#pragma unroll
    for (int u = 0; u < 4; ++u)
      *(half8*)(lv + tid * CSTR + u * 8) = *(const half8*)(hv + u * 8);
#pragma unroll
    for (int tap = 0; tap < 9; ++tap)
      gpart[tap * NPOS + tid] = p[tap];     // exclusive owner: plain ds_write
  }
  __syncthreads();

  // ---- compute: wave w8 owns tile row y0+w8; 18 chunks, 1 MFMA each ----
  const int lane = tid & 63, w8 = tid >> 6;   // w8 in 0..3
  const int ln = lane & 31, lh = lane >> 5;

  float gate = 0.f;
#pragma unroll
  for (int ki = 0; ki < 3; ++ki)
#pragma unroll
    for (int kj = 0; kj < 3; ++kj)
      gate += gpart[(ki * 3 + kj) * NPOS + (w8 + ki) * HTW + ln + kj];

  f32x16 acc;
#pragma unroll
  for (int i = 0; i < 16; ++i) acc[i] = 0.f;

#pragma unroll
  for (int q = 0; q < NCHUNK; ++q) {
    const int tap = q >> 1, h = q & 1;
    const int ki = tap / 3, kj = tap - ki * 3;
    const half8 a = *(const half8*)(Apack + ((q * 64 + lane) << 3));  // L1-hot
    const int off = ((w8 + ki) * HTW + ln + kj) * CSTR + h * 16 + lh * 8;
    const half8 bv = *(const half8*)(lv + off);   // ds_read_b128
    acc = __builtin_amdgcn_mfma_f32_32x32x16_f16(a, bv, acc, 0, 0, 0);
  }

  // ---- epilogue: D layout col=lane&31, row=(reg&3)+8*(reg>>2)+4*(lane>>5) ----
  const int voff_out = ((y0 + w8) << 8) + x0 + ln;
#pragma unroll
  for (int reg = 0; reg < 16; ++reg) {
    const int o = (reg & 3) + 8 * (reg >> 2) + 4 * lh;
    out[(((size_t)(bb * COUT + o)) << 16) + voff_out] = acc[reg] * gate + bias[o];
  }
}

extern "C" void kernel_launch(void* const* d_in, const int* in_sizes, int n_in,
                              void* d_out, int out_size, void* d_ws, size_t ws_size,
                              hipStream_t stream) {
  const float* x    = (const float*)d_in[0];
  const float* wgt  = (const float*)d_in[1];
  const float* dw   = (const float*)d_in[2];
  const float* bias = (const float*)d_in[3];
  float* out = (float*)d_out;

  _Float16* Apack = (_Float16*)d_ws;                 // 9216 f16 = 18432 B
  float* dwf      = (float*)((char*)d_ws + 18432);   // 288 f32

  prep_pack<<<(9216 + 288 + 255) / 256, 256, 0, stream>>>(wgt, dw, Apack, dwf);
  dynconv<<<BATCH * (HH / TH) * (WW / TW), 256, 0, stream>>>(x, Apack, dwf, bias, out);
}